// Round 9
// baseline (718.079 us; speedup 1.0000x reference)
//
#include <hip/hip_runtime.h>

#define NE   8
#define DIN  4096
#define DOUT 4096
#define TOK  8192

// fast path: 256x128 tile, BK=64, ring-3 K-tile pipeline, 512 threads
#define BM 256
#define BN 128
#define BKF 64
#define NKT (DIN / BKF)        // 64 K-tiles
#define BUFE 24576             // elems per ring buffer: A 16384 + B 8192 (48 KB)

// legacy fallback tile params
#define BK 32
#define LDSK 40

typedef __attribute__((ext_vector_type(4))) float f32x4;
typedef __attribute__((ext_vector_type(8))) short bf16x8;
typedef __attribute__((ext_vector_type(2))) unsigned long long u64x2;

#define AS1 __attribute__((address_space(1)))
#define AS3 __attribute__((address_space(3)))

static __device__ __forceinline__ unsigned short f2bf(float f) {
  unsigned u = __builtin_bit_cast(unsigned, f);
  u += 0x7fffu + ((u >> 16) & 1u);   // RTNE
  return (unsigned short)(u >> 16);
}

static __device__ __forceinline__ unsigned long long pack4(f32x4 v) {
  return (unsigned long long)f2bf(v[0])
       | ((unsigned long long)f2bf(v[1]) << 16)
       | ((unsigned long long)f2bf(v[2]) << 32)
       | ((unsigned long long)f2bf(v[3]) << 48);
}

static __device__ __forceinline__ void gload16(const void* g, void* l) {
  __builtin_amdgcn_global_load_lds((const AS1 unsigned int*)g,
                                   (AS3 unsigned int*)l, 16, 0, 0);
}

// ---------- fused prep: gating (fp32-exact) + x->bf16  AND  weights->bf16 ----------
__global__ void prep_kernel(const float* __restrict__ x, const float* __restrict__ gw,
                            const float* __restrict__ gb, int* __restrict__ counts,
                            int* __restrict__ tlist, unsigned short* __restrict__ xbf,
                            const float* __restrict__ ew, unsigned short* __restrict__ wbf) {
  if (blockIdx.x < TOK / 4) {
    const int lane = threadIdx.x & 63;
    const int tok  = blockIdx.x * 4 + (threadIdx.x >> 6);
    const float* xr = x + (size_t)tok * DIN;
    unsigned short* xo = xbf + (size_t)tok * DIN;
    float acc[NE];
    #pragma unroll
    for (int e = 0; e < NE; ++e) acc[e] = 0.f;
    for (int i = lane * 4; i < DIN; i += 256) {
      f32x4 xv = *(const f32x4*)(xr + i);
      *(unsigned long long*)(xo + i) = pack4(xv);
      #pragma unroll
      for (int e = 0; e < NE; ++e) {
        f32x4 wv = *(const f32x4*)(gw + e * DIN + i);
        acc[e] += xv[0]*wv[0] + xv[1]*wv[1] + xv[2]*wv[2] + xv[3]*wv[3];
      }
    }
    #pragma unroll
    for (int e = 0; e < NE; ++e) {
      float v = acc[e];
      #pragma unroll
      for (int o = 32; o > 0; o >>= 1) v += __shfl_xor(v, o);
      acc[e] = v;
    }
    if (lane == 0) {
      float bv = acc[0] + gb[0];
      int best = 0;
      #pragma unroll
      for (int e = 1; e < NE; ++e) {
        float v = acc[e] + gb[e];
        if (v > bv) { bv = v; best = e; }   // strict > == numpy first-max
      }
      int pos = atomicAdd(&counts[best], 1);
      tlist[best * TOK + pos] = tok;
    }
  } else {
    const int bid = blockIdx.x - TOK / 4;
    const size_t n = (size_t)NE * DOUT * DIN;
    size_t idx = ((size_t)bid * 256 + threadIdx.x) * 8;
    const size_t stride = (size_t)8192 * 256 * 8;
    for (; idx < n; idx += stride) {
      f32x4 a = *(const f32x4*)(ew + idx);
      f32x4 b = *(const f32x4*)(ew + idx + 4);
      u64x2 v; v[0] = pack4(a); v[1] = pack4(b);
      *(u64x2*)(wbf + idx) = v;
    }
  }
}

// ---------- fast grouped GEMM: 256x128, BK=64, ring-3, counted vmcnt(6) ----------
// Ring invariants (hand-verified):
//   read buf g%3; stage K-tile g+2 into buf (g+2)%3 != g%3; that buffer's
//   last reader (K-tile g-1) finished before g-1's final barrier, which
//   precedes any g-phase stage issue.
//   Load queue order: 6 loads per K-tile (A:4, B:2). Checkpoint before
//   K-tile g: outstanding = {g's 6 (issued at g-2), g+1's 6 (at g-1)};
//   vmcnt(6) certifies exactly g's 6, leaves 6 in flight -> never drains.
//   Frag-read swizzle identical to the round-2/7 measured-zero-conflict
//   pattern (128-B rows, slot=(ks*4+lk)^lr7, both-sides involution).
__global__ __launch_bounds__(512, 2)
void moe_gemm_bf(const unsigned short* __restrict__ xbf,
                 const unsigned short* __restrict__ wbf,
                 const float* __restrict__ eb,
                 const int* __restrict__ counts,
                 const int* __restrict__ tlist,
                 float* __restrict__ out) {
  __shared__ unsigned short lds[3 * BUFE];   // 144 KB
  __shared__ int rowtok[BM];

  const int tid = threadIdx.x;

  // XCD-bijective swizzle: 1280 blocks = 8 * 160; slot-major (A-panel L2 reuse)
  const int cpx  = gridDim.x >> 3;
  const int wgid = ((int)blockIdx.x & 7) * cpx + ((int)blockIdx.x >> 3);
  const int ntile = wgid & 31;
  const int slot  = wgid >> 5;

  int e = -1, mtile = 0, Me = 0;
  {
    int accn = 0;
    #pragma unroll
    for (int j = 0; j < NE; ++j) {
      int c = counts[j];
      int tt = (c + BM - 1) / BM;
      if (e < 0 && slot < accn + tt) { e = j; mtile = slot - accn; Me = c; }
      accn += tt;
    }
  }
  if (e < 0) return;

  const int n0 = ntile * BN;
  const int m0 = mtile * BM;
  const unsigned short* wbase = wbf + (size_t)e * DOUT * DIN;

  if (tid < BM) {
    int r = m0 + tid;
    rowtok[tid] = tlist[e * TOK + (r < Me ? r : Me - 1)];
  }
  __syncthreads();   // also drains all prior vmem -> clean vmcnt baseline

  const int w = tid >> 6, l = tid & 63;

  // staging: 512 thr -> (srow 0..63, sj 0..7); involution f(r)=r&7 on slot
  const int srow = tid >> 3, sj = tid & 7;
  const int colsw = (sj ^ (srow & 7)) * 8;
  const unsigned short* pa0 = xbf + (size_t)rowtok[srow]       * DIN + colsw;
  const unsigned short* pa1 = xbf + (size_t)rowtok[srow + 64]  * DIN + colsw;
  const unsigned short* pa2 = xbf + (size_t)rowtok[srow + 128] * DIN + colsw;
  const unsigned short* pa3 = xbf + (size_t)rowtok[srow + 192] * DIN + colsw;
  const unsigned short* pb0 = wbase + (size_t)(n0 + srow)      * DIN + colsw;
  const unsigned short* pb1 = wbase + (size_t)(n0 + srow + 64) * DIN + colsw;
  const int dw = w << 9;   // wave-uniform dest base within a 4096-elem chunk

  // frags: 8 waves as 4M x 2N; per-wave 64x64 out
  const int wm = w >> 1, wn = w & 1;
  const int lr = l & 15, lk = l >> 4, lr7 = l & 7;
  int offA[4], offB[4];
  #pragma unroll
  for (int mi = 0; mi < 4; ++mi) offA[mi] = (wm * 64 + mi * 16 + lr) * BKF;
  #pragma unroll
  for (int ni = 0; ni < 4; ++ni) offB[ni] = 16384 + (wn * 64 + ni * 16 + lr) * BKF;

  f32x4 acc[4][4];
  #pragma unroll
  for (int mi = 0; mi < 4; ++mi)
    #pragma unroll
    for (int ni = 0; ni < 4; ++ni) acc[mi][ni] = (f32x4){0.f, 0.f, 0.f, 0.f};

#define STAGE_A(gk, b) do { const int ko_ = (gk) * BKF;                       \
    const int d_ = (b) * BUFE + dw;                                           \
    gload16(pa0 + ko_, &lds[d_]);                                             \
    gload16(pa1 + ko_, &lds[d_ + 4096]);                                      \
    gload16(pa2 + ko_, &lds[d_ + 8192]);                                      \
    gload16(pa3 + ko_, &lds[d_ + 12288]); } while (0)
#define STAGE_B(gk, b) do { const int ko_ = (gk) * BKF;                       \
    const int d_ = (b) * BUFE + 16384 + dw;                                   \
    gload16(pb0 + ko_, &lds[d_]);                                             \
    gload16(pb1 + ko_, &lds[d_ + 4096]); } while (0)
#define PHASE(base, ks, STAGE_STMT) do {                                      \
    const int so_ = (((ks) * 4 + lk) ^ lr7) * 8;                              \
    bf16x8 av[4], bv[4];                                                      \
    _Pragma("unroll") for (int mi = 0; mi < 4; ++mi)                          \
      av[mi] = *(const bf16x8*)&lds[(base) + offA[mi] + so_];                 \
    _Pragma("unroll") for (int ni = 0; ni < 4; ++ni)                          \
      bv[ni] = *(const bf16x8*)&lds[(base) + offB[ni] + so_];                 \
    STAGE_STMT;                                                               \
    asm volatile("" ::: "memory");                                            \
    __builtin_amdgcn_s_barrier();                                             \
    asm volatile("" ::: "memory");                                            \
    __builtin_amdgcn_s_setprio(1);                                            \
    _Pragma("unroll") for (int mi = 0; mi < 4; ++mi)                          \
      _Pragma("unroll") for (int ni = 0; ni < 4; ++ni)                        \
        acc[mi][ni] = __builtin_amdgcn_mfma_f32_16x16x32_bf16(av[mi], bv[ni], acc[mi][ni], 0, 0, 0); \
    __builtin_amdgcn_s_setprio(0);                                            \
    asm volatile("" ::: "memory");                                            \
    __builtin_amdgcn_s_barrier();                                             \
    asm volatile("" ::: "memory");                                            \
  } while (0)

  // prologue: K-tile 0 -> buf0, K-tile 1 -> buf1 (12 loads; order A,A,A,A,B,B per tile)
  STAGE_A(0, 0); STAGE_B(0, 0);
  STAGE_A(1, 1); STAGE_B(1, 1);

  int bR = 0, bS = 2;
  for (int g = 0; g < NKT; ++g) {
    const int gk2 = (g + 2 < NKT) ? g + 2 : NKT - 1;   // clamped tail: never read
    // checkpoint: certify K-tile g landed (oldest 6); g+1's 6 stay in flight
    asm volatile("s_waitcnt vmcnt(6)" ::: "memory");
    __builtin_amdgcn_s_barrier();
    asm volatile("" ::: "memory");
    const int base = bR * BUFE;
    PHASE(base, 0, STAGE_A(gk2, bS));
    PHASE(base, 1, STAGE_B(gk2, bS));
    bR = (bR == 2) ? 0 : bR + 1;
    bS = (bS == 2) ? 0 : bS + 1;
  }

  // epilogue: bias + guarded scatter (C/D: col = lane&15, row = (lane>>4)*4 + j)
  float bias[4];
  #pragma unroll
  for (int ni = 0; ni < 4; ++ni) bias[ni] = eb[e * DOUT + n0 + wn * 64 + ni * 16 + lr];

  #pragma unroll
  for (int mi = 0; mi < 4; ++mi) {
    #pragma unroll
    for (int j = 0; j < 4; ++j) {
      int rloc = wm * 64 + mi * 16 + lk * 4 + j;
      if (m0 + rloc < Me) {
        int tokr = rowtok[rloc];
        float* op = out + (size_t)tokr * DOUT + n0 + wn * 64;
        #pragma unroll
        for (int ni = 0; ni < 4; ++ni)
          op[ni * 16 + lr] = acc[mi][ni][j] + bias[ni];
      }
    }
  }
#undef STAGE_A
#undef STAGE_B
#undef PHASE
}

// ================= legacy fallback path (used only if ws too small) ==========
__global__ void gate_kernel(const float* __restrict__ x, const float* __restrict__ gw,
                            const float* __restrict__ gb, int* __restrict__ counts,
                            int* __restrict__ tlist) {
  const int lane = threadIdx.x & 63;
  const int tok  = blockIdx.x * 4 + (threadIdx.x >> 6);
  const float* xr = x + (size_t)tok * DIN;
  float acc[NE];
  #pragma unroll
  for (int e = 0; e < NE; ++e) acc[e] = 0.f;
  for (int i = lane; i < DIN; i += 64) {
    float xv = xr[i];
    #pragma unroll
    for (int e = 0; e < NE; ++e) acc[e] += xv * gw[e * DIN + i];
  }
  #pragma unroll
  for (int e = 0; e < NE; ++e) {
    float v = acc[e];
    #pragma unroll
    for (int o = 32; o > 0; o >>= 1) v += __shfl_xor(v, o);
    acc[e] = v;
  }
  if (lane == 0) {
    float bv = acc[0] + gb[0];
    int best = 0;
    #pragma unroll
    for (int e = 1; e < NE; ++e) {
      float v = acc[e] + gb[e];
      if (v > bv) { bv = v; best = e; }
    }
    int pos = atomicAdd(&counts[best], 1);
    tlist[best * TOK + pos] = tok;
  }
}

__global__ __launch_bounds__(256, 2)
void moe_gemm(const float* __restrict__ x, const float* __restrict__ ew,
              const float* __restrict__ eb, const int* __restrict__ counts,
              const int* __restrict__ tlist, float* __restrict__ out) {
  __shared__ unsigned short fA[2][128 * LDSK];
  __shared__ unsigned short fB[2][128 * LDSK];
  __shared__ int rowtok[128];

  const int tid  = threadIdx.x;
  const int slot = blockIdx.y;

  int e = -1, mtile = 0, Me = 0;
  {
    int acc = 0;
    #pragma unroll
    for (int j = 0; j < NE; ++j) {
      int c = counts[j];
      int t = (c + 127) / 128;
      if (e < 0 && slot < acc + t) { e = j; mtile = slot - acc; Me = c; }
      acc += t;
    }
  }
  if (e < 0) return;

  const int n0 = blockIdx.x * 128;
  const int m0 = mtile * 128;
  const float* we = ew + (size_t)e * DOUT * DIN;

  if (tid < 128) {
    int r = m0 + tid;
    rowtok[tid] = tlist[e * TOK + (r < Me ? r : Me - 1)];
  }
  __syncthreads();

  const int srow = tid >> 3;
  const int scol = (tid & 7) * 4;
  const int lane = tid & 63;
  const int w  = tid >> 6;
  const int wr = (w >> 1) * 64;
  const int wc = (w & 1) * 64;
  const int lr = lane & 15;
  const int lk = lane >> 4;

  f32x4 accf[4][4];
  #pragma unroll
  for (int m = 0; m < 4; ++m)
    #pragma unroll
    for (int n = 0; n < 4; ++n) accf[m][n] = (f32x4){0.f, 0.f, 0.f, 0.f};

  const float* aptr[4];
  const float* bptr[4];
  #pragma unroll
  for (int p = 0; p < 4; ++p) {
    int r = p * 32 + srow;
    aptr[p] = x  + (size_t)rowtok[r] * DIN + scol;
    bptr[p] = we + (size_t)(n0 + r)  * DIN + scol;
  }

  #pragma unroll
  for (int p = 0; p < 4; ++p) {
    int r = p * 32 + srow;
    *(unsigned long long*)&fA[0][r * LDSK + scol] = pack4(*(const f32x4*)(aptr[p]));
    *(unsigned long long*)&fB[0][r * LDSK + scol] = pack4(*(const f32x4*)(bptr[p]));
  }
  __syncthreads();

  int cur = 0;
  for (int kt = 0; kt < DIN / BK; ++kt) {
    f32x4 ra[4], rb[4];
    const bool more = (kt + 1 < DIN / BK);
    if (more) {
      const int koff = (kt + 1) * BK;
      #pragma unroll
      for (int p = 0; p < 4; ++p) {
        ra[p] = *(const f32x4*)(aptr[p] + koff);
        rb[p] = *(const f32x4*)(bptr[p] + koff);
      }
    }
    bf16x8 af[4], bfr[4];
    #pragma unroll
    for (int m = 0; m < 4; ++m)
      af[m] = *(const bf16x8*)&fA[cur][(wr + m * 16 + lr) * LDSK + lk * 8];
    #pragma unroll
    for (int n = 0; n < 4; ++n)
      bfr[n] = *(const bf16x8*)&fB[cur][(wc + n * 16 + lr) * LDSK + lk * 8];
    #pragma unroll
    for (int m = 0; m < 4; ++m)
      #pragma unroll
      for (int n = 0; n < 4; ++n)
        accf[m][n] = __builtin_amdgcn_mfma_f32_16x16x32_bf16(af[m], bfr[n], accf[m][n], 0, 0, 0);
    if (more) {
      #pragma unroll
      for (int p = 0; p < 4; ++p) {
        int r = p * 32 + srow;
        *(unsigned long long*)&fA[cur ^ 1][r * LDSK + scol] = pack4(ra[p]);
        *(unsigned long long*)&fB[cur ^ 1][r * LDSK + scol] = pack4(rb[p]);
      }
    }
    __syncthreads();
    cur ^= 1;
  }

  float bias[4];
  #pragma unroll
  for (int n = 0; n < 4; ++n) bias[n] = eb[e * DOUT + n0 + wc + n * 16 + lr];

  #pragma unroll
  for (int m = 0; m < 4; ++m) {
    #pragma unroll
    for (int j = 0; j < 4; ++j) {
      int rloc = wr + m * 16 + lk * 4 + j;
      if (m0 + rloc < Me) {
        int tokr = rowtok[rloc];
        float* op = out + (size_t)tokr * DOUT + n0 + wc;
        #pragma unroll
        for (int n = 0; n < 4; ++n)
          op[n * 16 + lr] = accf[m][n][j] + bias[n];
      }
    }
  }
}

extern "C" void kernel_launch(void* const* d_in, const int* in_sizes, int n_in,
                              void* d_out, int out_size, void* d_ws, size_t ws_size,
                              hipStream_t stream) {
  const float* x  = (const float*)d_in[0];
  const float* gw = (const float*)d_in[1];
  const float* gb = (const float*)d_in[2];
  const float* ew = (const float*)d_in[3];
  const float* eb = (const float*)d_in[4];
  float* out = (float*)d_out;

  // ws layout: counts[16] | tlist[8*8192] | @1MB xbf (64MB) | wbf (256MB)
  int* counts = (int*)d_ws;
  int* tlist  = counts + 16;
  const size_t XOFF = 1u << 20;
  const size_t WOFF = XOFF + (size_t)TOK * DIN * 2;
  const size_t NEED = WOFF + (size_t)NE * DOUT * DIN * 2;

  hipMemsetAsync(counts, 0, 16 * sizeof(int), stream);

  if (ws_size >= NEED) {
    unsigned short* xbf = (unsigned short*)((char*)d_ws + XOFF);
    unsigned short* wbf = (unsigned short*)((char*)d_ws + WOFF);
    prep_kernel<<<TOK / 4 + 8192, 256, 0, stream>>>(x, gw, gb, counts, tlist, xbf, ew, wbf);
    // 32 n-tiles x (TOK/256 + NE = 40) worst-case slots = 1280 blocks (8 | 1280)
    moe_gemm_bf<<<32 * (TOK / BM + NE), 512, 0, stream>>>(xbf, wbf, eb, counts, tlist, out);
  } else {
    gate_kernel<<<TOK / 4, 256, 0, stream>>>(x, gw, gb, counts, tlist);
    dim3 grid(DOUT / 128, TOK / 128 + NE, 1);
    moe_gemm<<<grid, 256, 0, stream>>>(x, ew, eb, counts, tlist, out);
  }
}

// Round 11
// 629.267 us; speedup vs baseline: 1.1411x; 1.1411x over previous
//
#include <hip/hip_runtime.h>

#define NE   8
#define DIN  4096
#define DOUT 4096
#define TOK  8192

#define BM 128
#define BN 128
#define BKF 64    // fast-path K-step (bf16 elems)

// legacy fallback tile params
#define BK 32
#define LDSK 40

// weight conversion: 32768 blocks x 256 thr x 16 elems = 134,217,728 = NE*DOUT*DIN
#define CONV_BLOCKS 32768

typedef __attribute__((ext_vector_type(4))) float f32x4;
typedef __attribute__((ext_vector_type(8))) short bf16x8;
typedef __attribute__((ext_vector_type(2))) unsigned long long u64x2;

#define AS1 __attribute__((address_space(1)))
#define AS3 __attribute__((address_space(3)))

static __device__ __forceinline__ unsigned short f2bf(float f) {
  unsigned u = __builtin_bit_cast(unsigned, f);
  u += 0x7fffu + ((u >> 16) & 1u);   // RTNE
  return (unsigned short)(u >> 16);
}

static __device__ __forceinline__ unsigned long long pack4(f32x4 v) {
  return (unsigned long long)f2bf(v[0])
       | ((unsigned long long)f2bf(v[1]) << 16)
       | ((unsigned long long)f2bf(v[2]) << 32)
       | ((unsigned long long)f2bf(v[3]) << 48);
}

static __device__ __forceinline__ f32x4 ntload4(const float* p) {
  return __builtin_nontemporal_load((const f32x4*)p);
}

static __device__ __forceinline__ void gload16(const void* g, void* l) {
  __builtin_amdgcn_global_load_lds((const AS1 unsigned int*)g,
                                   (AS3 unsigned int*)l, 16, 0, 0);
}

// ---------- fused prep: gating (fp32-exact) + x->bf16  AND  weights->bf16 ----------
// One-shot fp32 streams (x, ew) use NONTEMPORAL loads so they don't evict the
// bf16 outputs (xbf 64MB + wbf 256MB) from L2/L3 before the GEMM re-reads them.
__global__ void prep_kernel(const float* __restrict__ x, const float* __restrict__ gw,
                            const float* __restrict__ gb, int* __restrict__ counts,
                            int* __restrict__ tlist, unsigned short* __restrict__ xbf,
                            const float* __restrict__ ew, unsigned short* __restrict__ wbf) {
  if (blockIdx.x < TOK / 4) {
    // ---- gating + x conversion (4 tokens/block, 1 wave/token) ----
    const int lane = threadIdx.x & 63;
    const int tok  = blockIdx.x * 4 + (threadIdx.x >> 6);
    const float* xr = x + (size_t)tok * DIN;
    unsigned short* xo = xbf + (size_t)tok * DIN;
    float acc[NE];
    #pragma unroll
    for (int e = 0; e < NE; ++e) acc[e] = 0.f;
    for (int i = lane * 4; i < DIN; i += 256) {
      f32x4 xv = ntload4(xr + i);                 // x read exactly once -> NT
      *(unsigned long long*)(xo + i) = pack4(xv);
      #pragma unroll
      for (int e = 0; e < NE; ++e) {
        f32x4 wv = *(const f32x4*)(gw + e * DIN + i);   // gw reused -> cacheable
        acc[e] += xv[0]*wv[0] + xv[1]*wv[1] + xv[2]*wv[2] + xv[3]*wv[3];
      }
    }
    #pragma unroll
    for (int e = 0; e < NE; ++e) {
      float v = acc[e];
      #pragma unroll
      for (int o = 32; o > 0; o >>= 1) v += __shfl_xor(v, o);
      acc[e] = v;
    }
    if (lane == 0) {
      float bv = acc[0] + gb[0];
      int best = 0;
      #pragma unroll
      for (int e = 1; e < NE; ++e) {
        float v = acc[e] + gb[e];
        if (v > bv) { bv = v; best = e; }   // strict > == numpy first-max
      }
      int pos = atomicAdd(&counts[best], 1);
      tlist[best * TOK + pos] = tok;
    }
  } else {
    // ---- expert weights fp32 -> bf16: 16 elems/thread, exactly one pass ----
    // CONV_BLOCKS(32768) x 256 thr x 16 = 134,217,728 = NE*DOUT*DIN exactly.
    const size_t bid = blockIdx.x - TOK / 4;
    const size_t idx = (bid * 256 + threadIdx.x) * 16;
    f32x4 a0 = ntload4(ew + idx);
    f32x4 a1 = ntload4(ew + idx + 4);
    f32x4 a2 = ntload4(ew + idx + 8);
    f32x4 a3 = ntload4(ew + idx + 12);
    u64x2 v0; v0[0] = pack4(a0); v0[1] = pack4(a1);
    u64x2 v1; v1[0] = pack4(a2); v1[1] = pack4(a3);
    *(u64x2*)(wbf + idx)     = v0;
    *(u64x2*)(wbf + idx + 8) = v1;
  }
}

// ---------- fast grouped GEMM (round-7 proven config, verbatim) ----------
// 128x128, BK=64, single-buffer 2-barrier loop, global_load_lds width-16,
// pre-swizzled source: 341 us, MfmaUtil 37%, bank conflicts == 0.
__global__ __launch_bounds__(256, 2)
void moe_gemm_bf(const unsigned short* __restrict__ xbf,
                 const unsigned short* __restrict__ wbf,
                 const float* __restrict__ eb,
                 const int* __restrict__ counts,
                 const int* __restrict__ tlist,
                 float* __restrict__ out) {
  __shared__ unsigned short sA[BM * BKF];  // 16 KB, linear [128][64]
  __shared__ unsigned short sB[BN * BKF];  // 16 KB
  __shared__ int rowtok[BM];

  const int tid  = threadIdx.x;
  const int slot = blockIdx.y;

  int e = -1, mtile = 0, Me = 0;
  {
    int acc = 0;
    #pragma unroll
    for (int j = 0; j < NE; ++j) {
      int c = counts[j];
      int t = (c + BM - 1) / BM;
      if (e < 0 && slot < acc + t) { e = j; mtile = slot - acc; Me = c; }
      acc += t;
    }
  }
  if (e < 0) return;

  const int n0 = blockIdx.x * BN;
  const int m0 = mtile * BM;

  if (tid < BM) {
    int r = m0 + tid;
    rowtok[tid] = tlist[e * TOK + (r < Me ? r : Me - 1)];
  }
  __syncthreads();

  const int lane = tid & 63;
  const int w    = tid >> 6;
  // staging geometry: each wave chunk c stages 8 rows x 64 cols (1 KB)
  const int j8   = lane & 7;     // 16B slot within row
  const int rsub = lane >> 3;    // row within 8-row chunk
  const int colsw = ((j8 ^ rsub) * 8);  // pre-swizzled global elem offset (T2 involution)

  const unsigned short* ag[4];
  const unsigned short* bg[4];
  const unsigned short* wbase = wbf + (size_t)e * DOUT * DIN;
  #pragma unroll
  for (int c = 0; c < 4; ++c) {
    int row = (w * 4 + c) * 8 + rsub;
    ag[c] = xbf   + (size_t)rowtok[row] * DIN + colsw;
    bg[c] = wbase + (size_t)(n0 + row)  * DIN + colsw;
  }

  const int wr = (w >> 1) * 64;
  const int wc = (w & 1) * 64;
  const int lr = lane & 15;
  const int lk = lane >> 4;
  const int lr7 = lr & 7;

  f32x4 acc[4][4];
  #pragma unroll
  for (int m = 0; m < 4; ++m)
    #pragma unroll
    for (int n = 0; n < 4; ++n) acc[m][n] = (f32x4){0.f, 0.f, 0.f, 0.f};

  for (int kt = 0; kt < DIN / BKF; ++kt) {   // 64 K-tiles
    const int kofs = kt * BKF;
    #pragma unroll
    for (int c = 0; c < 4; ++c) {
      gload16(ag[c] + kofs, &sA[(w * 4 + c) * 512]);
      gload16(bg[c] + kofs, &sB[(w * 4 + c) * 512]);
    }
    __syncthreads();   // drains vmcnt before barrier (compiler-inserted)

    #pragma unroll
    for (int ks = 0; ks < 2; ++ks) {
      bf16x8 af[4], bfv[4];
      #pragma unroll
      for (int m = 0; m < 4; ++m)
        af[m] = *(const bf16x8*)&sA[(wr + m * 16 + lr) * BKF + (((ks * 4 + lk) ^ lr7) * 8)];
      #pragma unroll
      for (int n = 0; n < 4; ++n)
        bfv[n] = *(const bf16x8*)&sB[(wc + n * 16 + lr) * BKF + (((ks * 4 + lk) ^ lr7) * 8)];
      #pragma unroll
      for (int m = 0; m < 4; ++m)
        #pragma unroll
        for (int n = 0; n < 4; ++n)
          acc[m][n] = __builtin_amdgcn_mfma_f32_16x16x32_bf16(af[m], bfv[n], acc[m][n], 0, 0, 0);
    }
    __syncthreads();
  }

  // epilogue: bias + guarded scatter (C/D: col = lane&15, row = (lane>>4)*4 + j)
  float bias[4];
  #pragma unroll
  for (int n = 0; n < 4; ++n) bias[n] = eb[e * DOUT + n0 + wc + n * 16 + lr];

  #pragma unroll
  for (int m = 0; m < 4; ++m) {
    #pragma unroll
    for (int j = 0; j < 4; ++j) {
      int rloc = wr + m * 16 + lk * 4 + j;
      if (m0 + rloc < Me) {
        int tokr = rowtok[rloc];
        float* op = out + (size_t)tokr * DOUT + n0 + wc;
        #pragma unroll
        for (int n = 0; n < 4; ++n)
          op[n * 16 + lr] = acc[m][n][j] + bias[n];
      }
    }
  }
}

// ================= legacy fallback path (used only if ws too small) ==========
__global__ void gate_kernel(const float* __restrict__ x, const float* __restrict__ gw,
                            const float* __restrict__ gb, int* __restrict__ counts,
                            int* __restrict__ tlist) {
  const int lane = threadIdx.x & 63;
  const int tok  = blockIdx.x * 4 + (threadIdx.x >> 6);
  const float* xr = x + (size_t)tok * DIN;
  float acc[NE];
  #pragma unroll
  for (int e = 0; e < NE; ++e) acc[e] = 0.f;
  for (int i = lane; i < DIN; i += 64) {
    float xv = xr[i];
    #pragma unroll
    for (int e = 0; e < NE; ++e) acc[e] += xv * gw[e * DIN + i];
  }
  #pragma unroll
  for (int e = 0; e < NE; ++e) {
    float v = acc[e];
    #pragma unroll
    for (int o = 32; o > 0; o >>= 1) v += __shfl_xor(v, o);
    acc[e] = v;
  }
  if (lane == 0) {
    float bv = acc[0] + gb[0];
    int best = 0;
    #pragma unroll
    for (int e = 1; e < NE; ++e) {
      float v = acc[e] + gb[e];
      if (v > bv) { bv = v; best = e; }
    }
    int pos = atomicAdd(&counts[best], 1);
    tlist[best * TOK + pos] = tok;
  }
}

__global__ __launch_bounds__(256, 2)
void moe_gemm(const float* __restrict__ x, const float* __restrict__ ew,
              const float* __restrict__ eb, const int* __restrict__ counts,
              const int* __restrict__ tlist, float* __restrict__ out) {
  __shared__ unsigned short fA[2][BM * LDSK];
  __shared__ unsigned short fB[2][BM * LDSK];
  __shared__ int rowtok[BM];

  const int tid  = threadIdx.x;
  const int slot = blockIdx.y;

  int e = -1, mtile = 0, Me = 0;
  {
    int acc = 0;
    #pragma unroll
    for (int j = 0; j < NE; ++j) {
      int c = counts[j];
      int t = (c + BM - 1) / BM;
      if (e < 0 && slot < acc + t) { e = j; mtile = slot - acc; Me = c; }
      acc += t;
    }
  }
  if (e < 0) return;

  const int n0 = blockIdx.x * BM;
  const int m0 = mtile * BM;
  const float* we = ew + (size_t)e * DOUT * DIN;

  if (tid < BM) {
    int r = m0 + tid;
    rowtok[tid] = tlist[e * TOK + (r < Me ? r : Me - 1)];
  }
  __syncthreads();

  const int srow = tid >> 3;
  const int scol = (tid & 7) * 4;
  const int lane = tid & 63;
  const int w  = tid >> 6;
  const int wr = (w >> 1) * 64;
  const int wc = (w & 1) * 64;
  const int lr = lane & 15;
  const int lk = lane >> 4;

  f32x4 accf[4][4];
  #pragma unroll
  for (int m = 0; m < 4; ++m)
    #pragma unroll
    for (int n = 0; n < 4; ++n) accf[m][n] = (f32x4){0.f, 0.f, 0.f, 0.f};

  const float* aptr[4];
  const float* bptr[4];
  #pragma unroll
  for (int p = 0; p < 4; ++p) {
    int r = p * 32 + srow;
    aptr[p] = x  + (size_t)rowtok[r] * DIN + scol;
    bptr[p] = we + (size_t)(n0 + r)  * DIN + scol;
  }

  #pragma unroll
  for (int p = 0; p < 4; ++p) {
    int r = p * 32 + srow;
    *(unsigned long long*)&fA[0][r * LDSK + scol] = pack4(*(const f32x4*)(aptr[p]));
    *(unsigned long long*)&fB[0][r * LDSK + scol] = pack4(*(const f32x4*)(bptr[p]));
  }
  __syncthreads();

  int cur = 0;
  for (int kt = 0; kt < DIN / BK; ++kt) {
    f32x4 ra[4], rb[4];
    const bool more = (kt + 1 < DIN / BK);
    if (more) {
      const int koff = (kt + 1) * BK;
      #pragma unroll
      for (int p = 0; p < 4; ++p) {
        ra[p] = *(const f32x4*)(aptr[p] + koff);
        rb[p] = *(const f32x4*)(bptr[p] + koff);
      }
    }
    bf16x8 af[4], bfr[4];
    #pragma unroll
    for (int m = 0; m < 4; ++m)
      af[m] = *(const bf16x8*)&fA[cur][(wr + m * 16 + lr) * LDSK + lk * 8];
    #pragma unroll
    for (int n = 0; n < 4; ++n)
      bfr[n] = *(const bf16x8*)&fB[cur][(wc + n * 16 + lr) * LDSK + lk * 8];
    #pragma unroll
    for (int m = 0; m < 4; ++m)
      #pragma unroll
      for (int n = 0; n < 4; ++n)
        accf[m][n] = __builtin_amdgcn_mfma_f32_16x16x32_bf16(af[m], bfr[n], accf[m][n], 0, 0, 0);
    if (more) {
      #pragma unroll
      for (int p = 0; p < 4; ++p) {
        int r = p * 32 + srow;
        *(unsigned long long*)&fA[cur ^ 1][r * LDSK + scol] = pack4(ra[p]);
        *(unsigned long long*)&fB[cur ^ 1][r * LDSK + scol] = pack4(rb[p]);
      }
    }
    __syncthreads();
    cur ^= 1;
  }

  float bias[4];
  #pragma unroll
  for (int n = 0; n < 4; ++n) bias[n] = eb[e * DOUT + n0 + wc + n * 16 + lr];

  #pragma unroll
  for (int m = 0; m < 4; ++m) {
    #pragma unroll
    for (int j = 0; j < 4; ++j) {
      int rloc = wr + m * 16 + lk * 4 + j;
      if (m0 + rloc < Me) {
        int tokr = rowtok[rloc];
        float* op = out + (size_t)tokr * DOUT + n0 + wc;
        #pragma unroll
        for (int n = 0; n < 4; ++n)
          op[n * 16 + lr] = accf[m][n][j] + bias[n];
      }
    }
  }
}

extern "C" void kernel_launch(void* const* d_in, const int* in_sizes, int n_in,
                              void* d_out, int out_size, void* d_ws, size_t ws_size,
                              hipStream_t stream) {
  const float* x  = (const float*)d_in[0];
  const float* gw = (const float*)d_in[1];
  const float* gb = (const float*)d_in[2];
  const float* ew = (const float*)d_in[3];
  const float* eb = (const float*)d_in[4];
  float* out = (float*)d_out;

  // ws layout: counts[16] | tlist[8*8192] | @1MB xbf (64MB) | wbf (256MB)
  int* counts = (int*)d_ws;
  int* tlist  = counts + 16;
  const size_t XOFF = 1u << 20;
  const size_t WOFF = XOFF + (size_t)TOK * DIN * 2;
  const size_t NEED = WOFF + (size_t)NE * DOUT * DIN * 2;

  hipMemsetAsync(counts, 0, 16 * sizeof(int), stream);

  if (ws_size >= NEED) {
    unsigned short* xbf = (unsigned short*)((char*)d_ws + XOFF);
    unsigned short* wbf = (unsigned short*)((char*)d_ws + WOFF);
    prep_kernel<<<TOK / 4 + CONV_BLOCKS, 256, 0, stream>>>(x, gw, gb, counts, tlist, xbf, ew, wbf);
    dim3 grid(DOUT / BN, TOK / BM + NE, 1);   // 32 n-tiles x 72 worst-case m-slots
    moe_gemm_bf<<<grid, 256, 0, stream>>>(xbf, wbf, eb, counts, tlist, out);
  } else {
    gate_kernel<<<TOK / 4, 256, 0, stream>>>(x, gw, gb, counts, tlist);
    dim3 grid(DOUT / BM, TOK / BM + NE, 1);
    moe_gemm<<<grid, 256, 0, stream>>>(x, ew, eb, counts, tlist, out);
  }
}